// Round 6
// baseline (775.685 us; speedup 1.0000x reference)
//
#include <hip/hip_runtime.h>
#include <hip/hip_bf16.h>
#include <math.h>

// Problem constants (from reference setup_inputs)
#define NNODES 100000
#define F_IN   500
#define F_MID  64
#define F_OUT  40
#define KPAD   512     // F_IN padded to multiple of 32 for MFMA

typedef __attribute__((ext_vector_type(8))) short short8;   // 8 bf16 = 4 VGPRs
typedef __attribute__((ext_vector_type(4))) float f32x4;    // MFMA acc

__device__ __forceinline__ unsigned short f2bf(float f) {
    union { float f; unsigned u; } c; c.f = f;
    unsigned r = c.u + 0x7FFF + ((c.u >> 16) & 1);   // round-nearest-even
    return (unsigned short)(r >> 16);
}

// add 8 bf16 (packed in uint4) into 8 fp32 accumulators
__device__ __forceinline__ void bf8_acc(uint4 r, float* acc) {
    unsigned u[4] = {r.x, r.y, r.z, r.w};
#pragma unroll
    for (int i = 0; i < 4; i++) {
        union { unsigned v; float f; } lo, hi;
        lo.v = u[i] << 16;
        hi.v = u[i] & 0xffff0000u;
        acc[2 * i]     += lo.f;
        acc[2 * i + 1] += hi.f;
    }
}

// ---------------------------------------------------------------------------
// CSR build: histogram -> two-level exclusive scan -> fill via atomic cursors
// ---------------------------------------------------------------------------

__global__ void hist_kernel(const int* __restrict__ dst, int* __restrict__ cnt, int E) {
    int e = blockIdx.x * blockDim.x + threadIdx.x;
    if (e < E) atomicAdd(&cnt[dst[e]], 1);
}

__global__ __launch_bounds__(1024) void scan_local(const int* __restrict__ cnt,
                                                   int* __restrict__ row_start,
                                                   int* __restrict__ bsum, int n) {
    __shared__ int wsum[16];
    int t = threadIdx.x;
    int i = blockIdx.x * 1024 + t;
    int lane = t & 63, w = t >> 6;
    int v = (i < n) ? (cnt[i] + 1) : 0;
    int s = v;
#pragma unroll
    for (int off = 1; off < 64; off <<= 1) {
        int u = __shfl_up(s, off, 64);
        if (lane >= off) s += u;
    }
    if (lane == 63) wsum[w] = s;
    __syncthreads();
    if (w == 0) {
        int ws = (lane < 16) ? wsum[lane] : 0;
#pragma unroll
        for (int off = 1; off < 16; off <<= 1) {
            int u = __shfl_up(ws, off, 64);
            if (lane >= off) ws += u;
        }
        if (lane < 16) wsum[lane] = ws;
    }
    __syncthreads();
    int wexcl = (w > 0) ? wsum[w - 1] : 0;
    int incl = s + wexcl;
    if (i < n) row_start[i] = incl - v;
    if (t == 1023) bsum[blockIdx.x] = incl;
}

__global__ void scan_bsum(const int* __restrict__ bsum, int* __restrict__ boff, int nb) {
    __shared__ int wt[2];
    int t = threadIdx.x;            // 128 threads
    int lane = t & 63, w = t >> 6;
    int v = (t < nb) ? bsum[t] : 0;
    int s = v;
#pragma unroll
    for (int off = 1; off < 64; off <<= 1) {
        int u = __shfl_up(s, off, 64);
        if (lane >= off) s += u;
    }
    if (lane == 63) wt[w] = s;
    __syncthreads();
    int incl = s + ((w == 1) ? wt[0] : 0);
    if (t < nb) boff[t] = incl - v;
    if (t == 127) boff[nb] = incl;
}

__global__ __launch_bounds__(1024) void scan_apply(const int* __restrict__ cnt,
                                                   int* __restrict__ row_start,
                                                   int* __restrict__ cursor,
                                                   float* __restrict__ dinv,
                                                   const int* __restrict__ boff,
                                                   int n, int nb) {
    int i = blockIdx.x * 1024 + threadIdx.x;
    if (i < n) {
        int v = row_start[i] + boff[blockIdx.x];
        row_start[i] = v;
        cursor[i] = v;
        dinv[i] = rsqrtf((float)(cnt[i] + 1));
    }
    if (i == 0) row_start[n] = boff[nb];
}

__global__ void fill_kernel(const int* __restrict__ src, const int* __restrict__ dst,
                            int* __restrict__ cursor, int* __restrict__ csr_src,
                            int E, int total) {
    int e = blockIdx.x * blockDim.x + threadIdx.x;
    if (e >= total) return;
    int s, d;
    if (e < E) { s = src[e]; d = dst[e]; }
    else       { s = e - E; d = s; }
    int pos = atomicAdd(&cursor[d], 1);
    csr_src[pos] = s;
}

// ---------------------------------------------------------------------------
// W1 -> bf16, transposed, K padded: W1T[n][k], n<64, k<512
// ---------------------------------------------------------------------------
__global__ void w1t_prep(const float* __restrict__ W1, unsigned short* __restrict__ W1T) {
    int idx = blockIdx.x * blockDim.x + threadIdx.x;   // 64*512
    if (idx >= F_MID * KPAD) return;
    int n = idx >> 9;          // /512
    int k = idx & (KPAD - 1);
    float v = (k < F_IN) ? W1[k * F_MID + n] : 0.f;
    W1T[idx] = f2bf(v);
}

// ---------------------------------------------------------------------------
// GEMM1 (bf16 MFMA): h1b[100000,64](bf16) = (X @ W1) * dinv[row]
// ---------------------------------------------------------------------------
__global__ __launch_bounds__(256) void gemm1_kernel(const float* __restrict__ X,
                                                    const unsigned short* __restrict__ W1T,
                                                    const float* __restrict__ dinv,
                                                    unsigned short* __restrict__ h1b) {
    const int BM = 128, BK = 32;
    __shared__ __align__(16) unsigned short A_lds[BM][BK];   // 8 KB
    __shared__ __align__(16) unsigned short B_lds[F_MID][BK]; // 4 KB

    int tid  = threadIdx.x;
    int wave = tid >> 6;
    int lane = tid & 63;
    int block_row = blockIdx.x * BM;

    int ar = tid >> 1, ah = tid & 1;
    int agr = block_row + ar;
    if (agr >= NNODES) agr = NNODES - 1;          // clamp (dup row, stores guarded)
    const float* xrow = X + (size_t)agr * F_IN;
    int bn = tid >> 2, bc = tid & 3;

    int mcol = lane & 15, quad = lane >> 4;

    f32x4 acc[2][4];
#pragma unroll
    for (int t = 0; t < 2; t++)
#pragma unroll
        for (int c = 0; c < 4; c++) {
            f32x4 z = {0.f, 0.f, 0.f, 0.f};
            acc[t][c] = z;
        }

    float4 apf[4];
    uint4  bpf;
    auto load_tile = [&](int ks) {
#pragma unroll
        for (int i = 0; i < 4; i++) {
            int kg = ks * BK + ah * 16 + i * 4;
            if (kg < F_IN) apf[i] = *(const float4*)(xrow + kg);
            else           apf[i] = make_float4(0.f, 0.f, 0.f, 0.f);
        }
        bpf = *(const uint4*)(W1T + (size_t)bn * KPAD + ks * BK + bc * 8);
    };

    load_tile(0);

    const int NK = KPAD / BK;   // 16
    for (int ks = 0; ks < NK; ks++) {
        unsigned pk[8];
#pragma unroll
        for (int i = 0; i < 4; i++) {
            pk[2 * i]     = (unsigned)f2bf(apf[i].x) | ((unsigned)f2bf(apf[i].y) << 16);
            pk[2 * i + 1] = (unsigned)f2bf(apf[i].z) | ((unsigned)f2bf(apf[i].w) << 16);
        }
        *(uint4*)&A_lds[ar][ah * 16]     = make_uint4(pk[0], pk[1], pk[2], pk[3]);
        *(uint4*)&A_lds[ar][ah * 16 + 8] = make_uint4(pk[4], pk[5], pk[6], pk[7]);
        *(uint4*)&B_lds[bn][bc * 8] = bpf;
        __syncthreads();

        if (ks + 1 < NK) load_tile(ks + 1);

        short8 a0 = *(const short8*)&A_lds[wave * 32 + mcol][quad * 8];
        short8 a1 = *(const short8*)&A_lds[wave * 32 + 16 + mcol][quad * 8];
        short8 bf[4];
#pragma unroll
        for (int c = 0; c < 4; c++)
            bf[c] = *(const short8*)&B_lds[c * 16 + mcol][quad * 8];

#pragma unroll
        for (int c = 0; c < 4; c++) {
            acc[0][c] = __builtin_amdgcn_mfma_f32_16x16x32_bf16(a0, bf[c], acc[0][c], 0, 0, 0);
            acc[1][c] = __builtin_amdgcn_mfma_f32_16x16x32_bf16(a1, bf[c], acc[1][c], 0, 0, 0);
        }
        __syncthreads();
    }

#pragma unroll
    for (int t = 0; t < 2; t++)
#pragma unroll
        for (int reg = 0; reg < 4; reg++) {
            int gr = block_row + wave * 32 + t * 16 + quad * 4 + reg;
            if (gr < NNODES) {
                float sc = dinv[gr];
#pragma unroll
                for (int c = 0; c < 4; c++)
                    h1b[(size_t)gr * F_MID + c * 16 + mcol] = f2bf(acc[t][c][reg] * sc);
            }
        }
}

// ---------------------------------------------------------------------------
// Fused agg1 + gemm2: 4 nodes per 256-thread block (1 wave per node).
// launch_bounds(256,4) -> VGPR cap 128: batched gathers actually stay in
// flight. Per 64-edge window: 1 coalesced index load, 8 bpermute broadcasts,
// then ALL 8 row-gather loads issued into r[8] before any accumulate ->
// 2 serial memory round-trips per node instead of ~9.
// ---------------------------------------------------------------------------
__global__ __launch_bounds__(256, 4) void agg1_gemm2_kernel(const unsigned short* __restrict__ h1b,
                                                            const int* __restrict__ csr_src,
                                                            const int* __restrict__ row_start,
                                                            const float* __restrict__ dinv,
                                                            const float* __restrict__ b1,
                                                            const float* __restrict__ W2,
                                                            unsigned short* __restrict__ h2b) {
    __shared__ float W2s[F_MID * F_OUT];   // 10 KB
    int tid = threadIdx.x;
    for (int i = tid; i < F_MID * F_OUT; i += 256) W2s[i] = W2[i];
    __syncthreads();

    int node = blockIdx.x * 4 + (tid >> 6);
    int lane = tid & 63;
    int g = lane >> 3;          // edge slot within batch 0..7
    int f = lane & 7;           // feature octet: feats 8f..8f+7

    int s0 = row_start[node], s1 = row_start[node + 1];
    float fa[8] = {0, 0, 0, 0, 0, 0, 0, 0};

    for (int base = s0; base < s1; base += 64) {
        int cnt = s1 - base; if (cnt > 64) cnt = 64;
        int myidx = (lane < cnt) ? csr_src[base + lane] : 0;
        // broadcast the 8 edge indices this group will gather (slot j -> edge j*8+g)
        int idx[8];
#pragma unroll
        for (int j = 0; j < 8; j++) idx[j] = __shfl(myidx, j * 8 + g, 64);
        // issue ALL gathers, then accumulate (single waitcnt)
        uint4 r[8];
#pragma unroll
        for (int j = 0; j < 8; j++) {
            r[j] = make_uint4(0, 0, 0, 0);
            if (j * 8 + g < cnt)
                r[j] = *(const uint4*)&h1b[(size_t)idx[j] * F_MID + f * 8];
        }
#pragma unroll
        for (int j = 0; j < 8; j++) bf8_acc(r[j], fa);
    }
#pragma unroll
    for (int m = 8; m < 64; m <<= 1)
#pragma unroll
        for (int i = 0; i < 8; i++) fa[i] += __shfl_xor(fa[i], m, 64);
    // every lane: fa = full sums for feats 8f..8f+7 (replicated across g)

    float dn = dinv[node];
    float4 b1a = *(const float4*)&b1[f * 8];
    float4 b1b = *(const float4*)&b1[f * 8 + 4];
    float v8[8];
    v8[0] = fmaxf(fa[0] * dn + b1a.x, 0.f);
    v8[1] = fmaxf(fa[1] * dn + b1a.y, 0.f);
    v8[2] = fmaxf(fa[2] * dn + b1a.z, 0.f);
    v8[3] = fmaxf(fa[3] * dn + b1a.w, 0.f);
    v8[4] = fmaxf(fa[4] * dn + b1b.x, 0.f);
    v8[5] = fmaxf(fa[5] * dn + b1b.y, 0.f);
    v8[6] = fmaxf(fa[6] * dn + b1b.z, 0.f);
    v8[7] = fmaxf(fa[7] * dn + b1b.w, 0.f);

    // gemm2: o[cl] = sum_k v[k] * W2[k][cl]; v[k] lives on lane (k>>3), comp k&7
    int cl = (lane < F_OUT) ? lane : 0;
    float o = 0.f;
#pragma unroll
    for (int kg = 0; kg < 8; kg++) {
#pragma unroll
        for (int c = 0; c < 8; c++) {
            float vv = __shfl(v8[c], kg, 64);
            o = fmaf(vv, W2s[(8 * kg + c) * F_OUT + cl], o);
        }
    }
    if (lane < F_OUT) h2b[(size_t)node * F_MID + lane] = f2bf(o * dn);
}

// ---------------------------------------------------------------------------
// agg2 + bias + log_softmax: same batched-gather structure; bf16 h2 rows
// (stride 128 B, 40 used feats; lanes f<5 active for gathers).
// ---------------------------------------------------------------------------
__global__ __launch_bounds__(256, 4) void agg2_softmax_kernel(const unsigned short* __restrict__ h2b,
                                                              const int* __restrict__ csr_src,
                                                              const int* __restrict__ row_start,
                                                              const float* __restrict__ dinv,
                                                              const float* __restrict__ b2,
                                                              float* __restrict__ out) {
    int tid = threadIdx.x;
    int node = blockIdx.x * 4 + (tid >> 6);
    int lane = tid & 63;
    int g = lane >> 3;
    int f = lane & 7;
    bool act = (f < 5);        // 5 octets = 40 classes

    int s0 = row_start[node], s1 = row_start[node + 1];
    float fa[8] = {0, 0, 0, 0, 0, 0, 0, 0};

    for (int base = s0; base < s1; base += 64) {
        int cnt = s1 - base; if (cnt > 64) cnt = 64;
        int myidx = (lane < cnt) ? csr_src[base + lane] : 0;
        int idx[8];
#pragma unroll
        for (int j = 0; j < 8; j++) idx[j] = __shfl(myidx, j * 8 + g, 64);
        uint4 r[8];
#pragma unroll
        for (int j = 0; j < 8; j++) {
            r[j] = make_uint4(0, 0, 0, 0);
            if (act && j * 8 + g < cnt)
                r[j] = *(const uint4*)&h2b[(size_t)idx[j] * F_MID + f * 8];
        }
#pragma unroll
        for (int j = 0; j < 8; j++) bf8_acc(r[j], fa);
    }
#pragma unroll
    for (int m = 8; m < 64; m <<= 1)
#pragma unroll
        for (int i = 0; i < 8; i++) fa[i] += __shfl_xor(fa[i], m, 64);

    float dn = dinv[node];
    float z[8];
    if (act) {
        float4 b2a = *(const float4*)&b2[f * 8];
        float4 b2b = *(const float4*)&b2[f * 8 + 4];
        z[0] = fa[0] * dn + b2a.x; z[1] = fa[1] * dn + b2a.y;
        z[2] = fa[2] * dn + b2a.z; z[3] = fa[3] * dn + b2a.w;
        z[4] = fa[4] * dn + b2b.x; z[5] = fa[5] * dn + b2b.y;
        z[6] = fa[6] * dn + b2b.z; z[7] = fa[7] * dn + b2b.w;
    } else {
#pragma unroll
        for (int i = 0; i < 8; i++) z[i] = -3.4e38f;
    }
    float m = z[0];
#pragma unroll
    for (int i = 1; i < 8; i++) m = fmaxf(m, z[i]);
#pragma unroll
    for (int off = 1; off < 8; off <<= 1) m = fmaxf(m, __shfl_xor(m, off, 64));
    float s = 0.f;
    if (act) {
#pragma unroll
        for (int i = 0; i < 8; i++) s += __expf(z[i] - m);
    }
#pragma unroll
    for (int off = 1; off < 8; off <<= 1) s += __shfl_xor(s, off, 64);
    float lse = m + logf(s);
    if (act && g == 0) {
        float4 o0 = make_float4(z[0] - lse, z[1] - lse, z[2] - lse, z[3] - lse);
        float4 o1 = make_float4(z[4] - lse, z[5] - lse, z[6] - lse, z[7] - lse);
        *(float4*)&out[(size_t)node * F_OUT + f * 8]     = o0;
        *(float4*)&out[(size_t)node * F_OUT + f * 8 + 4] = o1;
    }
}

// ---------------------------------------------------------------------------
extern "C" void kernel_launch(void* const* d_in, const int* in_sizes, int n_in,
                              void* d_out, int out_size, void* d_ws, size_t ws_size,
                              hipStream_t stream) {
    const float* X   = (const float*)d_in[0];
    const int*   ei  = (const int*)d_in[1];
    const float* W1  = (const float*)d_in[2];
    const float* b1  = (const float*)d_in[3];
    const float* W2  = (const float*)d_in[4];
    const float* b2  = (const float*)d_in[5];
    float* out = (float*)d_out;

    const int N = NNODES;
    const int E = in_sizes[1] / 2;      // 1,600,000
    const int TOTAL = E + N;
    const int* srcv = ei;
    const int* dstv = ei + E;

    char* p = (char*)d_ws;
    auto carve = [&](size_t bytes) {
        void* r = (void*)p;
        p += (bytes + 255) & ~(size_t)255;
        return r;
    };
    int*   cnt       = (int*)carve((size_t)N * 4);
    int*   row_start = (int*)carve((size_t)(N + 1) * 4);
    int*   cursor    = (int*)carve((size_t)N * 4);
    int*   bsum      = (int*)carve(512);
    int*   boff      = (int*)carve(512 + 4);
    int*   csr_src   = (int*)carve((size_t)TOTAL * 4);
    float* dinv      = (float*)carve((size_t)N * 4);
    unsigned short* W1T = (unsigned short*)carve((size_t)F_MID * KPAD * 2);
    unsigned short* h1b = (unsigned short*)carve((size_t)N * F_MID * 2);
    unsigned short* h2b = (unsigned short*)carve((size_t)N * F_MID * 2);
    (void)ws_size; (void)n_in; (void)out_size;

    const int nb = (N + 1023) / 1024;   // 98

    hipMemsetAsync(cnt, 0, (size_t)N * 4, stream);
    hist_kernel<<<(E + 255) / 256, 256, 0, stream>>>(dstv, cnt, E);
    scan_local<<<nb, 1024, 0, stream>>>(cnt, row_start, bsum, N);
    scan_bsum<<<1, 128, 0, stream>>>(bsum, boff, nb);
    scan_apply<<<nb, 1024, 0, stream>>>(cnt, row_start, cursor, dinv, boff, N, nb);
    fill_kernel<<<(TOTAL + 255) / 256, 256, 0, stream>>>(srcv, dstv, cursor, csr_src, E, TOTAL);
    w1t_prep<<<(F_MID * KPAD + 255) / 256, 256, 0, stream>>>(W1, W1T);

    gemm1_kernel<<<(N + 127) / 128, 256, 0, stream>>>(X, W1T, dinv, h1b);
    agg1_gemm2_kernel<<<N / 4, 256, 0, stream>>>(h1b, csr_src, row_start, dinv, b1, W2, h2b);
    agg2_softmax_kernel<<<N / 4, 256, 0, stream>>>(h2b, csr_src, row_start, dinv, b2, out);
}

// Round 7
// 655.600 us; speedup vs baseline: 1.1832x; 1.1832x over previous
//
#include <hip/hip_runtime.h>
#include <hip/hip_bf16.h>
#include <math.h>

// Problem constants (from reference setup_inputs)
#define NNODES 100000
#define F_IN   500
#define F_MID  64
#define F_OUT  40
#define KPAD   512     // F_IN padded to multiple of 32 for MFMA
#define H2S    48      // h2 row stride (40 classes + 8 zero pad cols)

typedef __attribute__((ext_vector_type(8))) short short8;   // 8 bf16 = 4 VGPRs
typedef __attribute__((ext_vector_type(4))) float f32x4;    // MFMA acc

__device__ __forceinline__ unsigned short f2bf(float f) {
    union { float f; unsigned u; } c; c.f = f;
    unsigned r = c.u + 0x7FFF + ((c.u >> 16) & 1);   // round-nearest-even
    return (unsigned short)(r >> 16);
}
__device__ __forceinline__ float bf2f(unsigned short u) {
    union { unsigned v; float f; } c; c.v = ((unsigned)u) << 16; return c.f;
}

// ---------------------------------------------------------------------------
// CSR build: histogram -> two-level exclusive scan -> fill via atomic cursors
// ---------------------------------------------------------------------------

__global__ void hist_kernel(const int* __restrict__ dst, int* __restrict__ cnt, int E) {
    int e = blockIdx.x * blockDim.x + threadIdx.x;
    if (e < E) atomicAdd(&cnt[dst[e]], 1);
}

__global__ __launch_bounds__(1024) void scan_local(const int* __restrict__ cnt,
                                                   int* __restrict__ row_start,
                                                   int* __restrict__ bsum, int n) {
    __shared__ int wsum[16];
    int t = threadIdx.x;
    int i = blockIdx.x * 1024 + t;
    int lane = t & 63, w = t >> 6;
    int v = (i < n) ? (cnt[i] + 1) : 0;
    int s = v;
#pragma unroll
    for (int off = 1; off < 64; off <<= 1) {
        int u = __shfl_up(s, off, 64);
        if (lane >= off) s += u;
    }
    if (lane == 63) wsum[w] = s;
    __syncthreads();
    if (w == 0) {
        int ws = (lane < 16) ? wsum[lane] : 0;
#pragma unroll
        for (int off = 1; off < 16; off <<= 1) {
            int u = __shfl_up(ws, off, 64);
            if (lane >= off) ws += u;
        }
        if (lane < 16) wsum[lane] = ws;
    }
    __syncthreads();
    int wexcl = (w > 0) ? wsum[w - 1] : 0;
    int incl = s + wexcl;
    if (i < n) row_start[i] = incl - v;
    if (t == 1023) bsum[blockIdx.x] = incl;
}

__global__ void scan_bsum(const int* __restrict__ bsum, int* __restrict__ boff, int nb) {
    __shared__ int wt[2];
    int t = threadIdx.x;            // 128 threads
    int lane = t & 63, w = t >> 6;
    int v = (t < nb) ? bsum[t] : 0;
    int s = v;
#pragma unroll
    for (int off = 1; off < 64; off <<= 1) {
        int u = __shfl_up(s, off, 64);
        if (lane >= off) s += u;
    }
    if (lane == 63) wt[w] = s;
    __syncthreads();
    int incl = s + ((w == 1) ? wt[0] : 0);
    if (t < nb) boff[t] = incl - v;
    if (t == 127) boff[nb] = incl;
}

__global__ __launch_bounds__(1024) void scan_apply(const int* __restrict__ cnt,
                                                   int* __restrict__ row_start,
                                                   int* __restrict__ cursor,
                                                   float* __restrict__ dinv,
                                                   const int* __restrict__ boff,
                                                   int n, int nb) {
    int i = blockIdx.x * 1024 + threadIdx.x;
    if (i < n) {
        int v = row_start[i] + boff[blockIdx.x];
        row_start[i] = v;
        cursor[i] = v;
        dinv[i] = rsqrtf((float)(cnt[i] + 1));
    }
    if (i == 0) row_start[n] = boff[nb];
}

__global__ void fill_kernel(const int* __restrict__ src, const int* __restrict__ dst,
                            int* __restrict__ cursor, int* __restrict__ csr_src,
                            int E, int total) {
    int e = blockIdx.x * blockDim.x + threadIdx.x;
    if (e >= total) return;
    int s, d;
    if (e < E) { s = src[e]; d = dst[e]; }
    else       { s = e - E; d = s; }
    int pos = atomicAdd(&cursor[d], 1);
    csr_src[pos] = s;
}

// ---------------------------------------------------------------------------
// W1 -> bf16, transposed, K padded: W1T[n][k], n<64, k<512
// ---------------------------------------------------------------------------
__global__ void w1t_prep(const float* __restrict__ W1, unsigned short* __restrict__ W1T) {
    int idx = blockIdx.x * blockDim.x + threadIdx.x;   // 64*512
    if (idx >= F_MID * KPAD) return;
    int n = idx >> 9;          // /512
    int k = idx & (KPAD - 1);
    float v = (k < F_IN) ? W1[k * F_MID + n] : 0.f;
    W1T[idx] = f2bf(v);
}

// W2 -> bf16, transposed, padded: W2T[col][k], col<48 (40 real), k<64
__global__ void w2t_prep(const float* __restrict__ W2, unsigned short* __restrict__ W2T) {
    int idx = blockIdx.x * blockDim.x + threadIdx.x;   // 48*64
    if (idx >= H2S * F_MID) return;
    int c = idx >> 6;
    int k = idx & 63;
    float v = (c < F_OUT) ? W2[k * F_OUT + c] : 0.f;
    W2T[idx] = f2bf(v);
}

// ---------------------------------------------------------------------------
// GEMM1 (bf16 MFMA): h1b[100000,64](bf16) = (X @ W1) * dinv[row]
// ---------------------------------------------------------------------------
__global__ __launch_bounds__(256) void gemm1_kernel(const float* __restrict__ X,
                                                    const unsigned short* __restrict__ W1T,
                                                    const float* __restrict__ dinv,
                                                    unsigned short* __restrict__ h1b) {
    const int BM = 128, BK = 32;
    __shared__ __align__(16) unsigned short A_lds[BM][BK];   // 8 KB
    __shared__ __align__(16) unsigned short B_lds[F_MID][BK]; // 4 KB

    int tid  = threadIdx.x;
    int wave = tid >> 6;
    int lane = tid & 63;
    int block_row = blockIdx.x * BM;

    int ar = tid >> 1, ah = tid & 1;
    int agr = block_row + ar;
    if (agr >= NNODES) agr = NNODES - 1;          // clamp (dup row, stores guarded)
    const float* xrow = X + (size_t)agr * F_IN;
    int bn = tid >> 2, bc = tid & 3;

    int mcol = lane & 15, quad = lane >> 4;

    f32x4 acc[2][4];
#pragma unroll
    for (int t = 0; t < 2; t++)
#pragma unroll
        for (int c = 0; c < 4; c++) {
            f32x4 z = {0.f, 0.f, 0.f, 0.f};
            acc[t][c] = z;
        }

    float4 apf[4];
    uint4  bpf;
    auto load_tile = [&](int ks) {
#pragma unroll
        for (int i = 0; i < 4; i++) {
            int kg = ks * BK + ah * 16 + i * 4;
            if (kg < F_IN) apf[i] = *(const float4*)(xrow + kg);
            else           apf[i] = make_float4(0.f, 0.f, 0.f, 0.f);
        }
        bpf = *(const uint4*)(W1T + (size_t)bn * KPAD + ks * BK + bc * 8);
    };

    load_tile(0);

    const int NK = KPAD / BK;   // 16
    for (int ks = 0; ks < NK; ks++) {
        unsigned pk[8];
#pragma unroll
        for (int i = 0; i < 4; i++) {
            pk[2 * i]     = (unsigned)f2bf(apf[i].x) | ((unsigned)f2bf(apf[i].y) << 16);
            pk[2 * i + 1] = (unsigned)f2bf(apf[i].z) | ((unsigned)f2bf(apf[i].w) << 16);
        }
        *(uint4*)&A_lds[ar][ah * 16]     = make_uint4(pk[0], pk[1], pk[2], pk[3]);
        *(uint4*)&A_lds[ar][ah * 16 + 8] = make_uint4(pk[4], pk[5], pk[6], pk[7]);
        *(uint4*)&B_lds[bn][bc * 8] = bpf;
        __syncthreads();

        if (ks + 1 < NK) load_tile(ks + 1);

        short8 a0 = *(const short8*)&A_lds[wave * 32 + mcol][quad * 8];
        short8 a1 = *(const short8*)&A_lds[wave * 32 + 16 + mcol][quad * 8];
        short8 bf[4];
#pragma unroll
        for (int c = 0; c < 4; c++)
            bf[c] = *(const short8*)&B_lds[c * 16 + mcol][quad * 8];

#pragma unroll
        for (int c = 0; c < 4; c++) {
            acc[0][c] = __builtin_amdgcn_mfma_f32_16x16x32_bf16(a0, bf[c], acc[0][c], 0, 0, 0);
            acc[1][c] = __builtin_amdgcn_mfma_f32_16x16x32_bf16(a1, bf[c], acc[1][c], 0, 0, 0);
        }
        __syncthreads();
    }

#pragma unroll
    for (int t = 0; t < 2; t++)
#pragma unroll
        for (int reg = 0; reg < 4; reg++) {
            int gr = block_row + wave * 32 + t * 16 + quad * 4 + reg;
            if (gr < NNODES) {
                float sc = dinv[gr];
#pragma unroll
                for (int c = 0; c < 4; c++)
                    h1b[(size_t)gr * F_MID + c * 16 + mcol] = f2bf(acc[t][c][reg] * sc);
            }
        }
}

// ---------------------------------------------------------------------------
// agg1: 4 nodes per 256-thread block, one wave per node, lane = feature.
// In-lane accumulation -> ZERO cross-lane / LDS ops in the hot path.
// Indices: wave-uniform scalar loads, 8-edge batches with next-batch prefetch.
// out1b[node][lane] = bf16(relu(acc*dinv + b1))
// ---------------------------------------------------------------------------
__global__ __launch_bounds__(256) void agg1_kernel(const unsigned short* __restrict__ h1b,
                                                   const int* __restrict__ csr_src,
                                                   const int* __restrict__ row_start,
                                                   const float* __restrict__ dinv,
                                                   const float* __restrict__ b1,
                                                   unsigned short* __restrict__ out1b) {
    int tid = threadIdx.x;
    int node = blockIdx.x * 4 + (tid >> 6);
    int lane = tid & 63;

    int s0 = row_start[node], s1 = row_start[node + 1];
    float acc = 0.f;

    int idx[8];
    int e = s0;
#pragma unroll
    for (int j = 0; j < 8; j++) {
        int p = e + j; if (p > s1 - 1) p = s1 - 1;
        idx[j] = csr_src[p];          // uniform address -> scalar load
    }
    while (e < s1) {
        int cnt = s1 - e;             // >= 1, wave-uniform
        int cidx[8];
#pragma unroll
        for (int j = 0; j < 8; j++) cidx[j] = idx[j];
        int en = e + 8;
        if (en < s1) {
#pragma unroll
            for (int j = 0; j < 8; j++) {
                int p = en + j; if (p > s1 - 1) p = s1 - 1;
                idx[j] = csr_src[p];  // prefetch next batch (scalar)
            }
        }
#pragma unroll
        for (int j = 0; j < 8; j++) {
            float v = bf2f(h1b[(size_t)cidx[j] * F_MID + lane]);
            if (j < cnt) acc += v;    // wave-uniform predicate
        }
        e = en;
    }

    float dn = dinv[node];
    float v = fmaxf(acc * dn + b1[lane], 0.f);
    out1b[(size_t)node * F_MID + lane] = f2bf(v);
}

// ---------------------------------------------------------------------------
// GEMM2 (bf16 MFMA, no LDS): h2b[100000,48](bf16) = (out1 @ W2pad) * dinv[row]
// Block = 256 thr = 4 waves; wave handles 16 nodes x 48 cols:
// 2 k-steps x 3 col tiles of mfma_f32_16x16x32_bf16. Cols 40..47 are zero
// (W2T zero-padded) so agg2 can over-read them harmlessly.
// ---------------------------------------------------------------------------
__global__ __launch_bounds__(256) void gemm2_kernel(const unsigned short* __restrict__ out1b,
                                                    const unsigned short* __restrict__ W2T,
                                                    const float* __restrict__ dinv,
                                                    unsigned short* __restrict__ h2b) {
    int tid = threadIdx.x;
    int wave = tid >> 6;
    int lane = tid & 63;
    int n0 = blockIdx.x * 64 + wave * 16;     // 16 nodes per wave
    int m = lane & 15, quad = lane >> 4;

    int arow = n0 + m; if (arow >= NNODES) arow = NNODES - 1;

    f32x4 acc[3];
#pragma unroll
    for (int c = 0; c < 3; c++) { f32x4 z = {0.f, 0.f, 0.f, 0.f}; acc[c] = z; }

#pragma unroll
    for (int t = 0; t < 2; t++) {
        short8 a = *(const short8*)&out1b[(size_t)arow * F_MID + t * 32 + quad * 8];
#pragma unroll
        for (int c = 0; c < 3; c++) {
            short8 b = *(const short8*)&W2T[(size_t)(c * 16 + m) * F_MID + t * 32 + quad * 8];
            acc[c] = __builtin_amdgcn_mfma_f32_16x16x32_bf16(a, b, acc[c], 0, 0, 0);
        }
    }

#pragma unroll
    for (int reg = 0; reg < 4; reg++) {
        int gr = n0 + quad * 4 + reg;
        if (gr < NNODES) {
            float dn = dinv[gr];
#pragma unroll
            for (int c = 0; c < 3; c++)
                h2b[(size_t)gr * H2S + c * 16 + m] = f2bf(acc[c][reg] * dn);
        }
    }
}

// ---------------------------------------------------------------------------
// agg2 + bias + log_softmax: 4 nodes/block, lane = class (lanes 0..47 gather,
// cols 40..47 are zeros; softmax over lanes 0..39). Only ~12 shfls per node.
// ---------------------------------------------------------------------------
__global__ __launch_bounds__(256) void agg2_softmax_kernel(const unsigned short* __restrict__ h2b,
                                                           const int* __restrict__ csr_src,
                                                           const int* __restrict__ row_start,
                                                           const float* __restrict__ dinv,
                                                           const float* __restrict__ b2,
                                                           float* __restrict__ out) {
    int tid = threadIdx.x;
    int node = blockIdx.x * 4 + (tid >> 6);
    int lane = tid & 63;
    int cl = (lane < H2S) ? lane : 0;

    int s0 = row_start[node], s1 = row_start[node + 1];
    float acc = 0.f;

    int idx[8];
    int e = s0;
#pragma unroll
    for (int j = 0; j < 8; j++) {
        int p = e + j; if (p > s1 - 1) p = s1 - 1;
        idx[j] = csr_src[p];
    }
    while (e < s1) {
        int cnt = s1 - e;
        int cidx[8];
#pragma unroll
        for (int j = 0; j < 8; j++) cidx[j] = idx[j];
        int en = e + 8;
        if (en < s1) {
#pragma unroll
            for (int j = 0; j < 8; j++) {
                int p = en + j; if (p > s1 - 1) p = s1 - 1;
                idx[j] = csr_src[p];
            }
        }
#pragma unroll
        for (int j = 0; j < 8; j++) {
            float v = bf2f(h2b[(size_t)cidx[j] * H2S + cl]);
            if (j < cnt) acc += v;
        }
        e = en;
    }

    float dn = dinv[node];
    bool act = (lane < F_OUT);
    float z = act ? (acc * dn + b2[cl]) : -3.4e38f;
    float m = z;
#pragma unroll
    for (int off = 1; off < 64; off <<= 1) m = fmaxf(m, __shfl_xor(m, off, 64));
    float p = act ? __expf(z - m) : 0.f;
#pragma unroll
    for (int off = 1; off < 64; off <<= 1) p += __shfl_xor(p, off, 64);
    float lse = m + logf(p);
    if (act) out[(size_t)node * F_OUT + lane] = z - lse;
}

// ---------------------------------------------------------------------------
extern "C" void kernel_launch(void* const* d_in, const int* in_sizes, int n_in,
                              void* d_out, int out_size, void* d_ws, size_t ws_size,
                              hipStream_t stream) {
    const float* X   = (const float*)d_in[0];
    const int*   ei  = (const int*)d_in[1];
    const float* W1  = (const float*)d_in[2];
    const float* b1  = (const float*)d_in[3];
    const float* W2  = (const float*)d_in[4];
    const float* b2  = (const float*)d_in[5];
    float* out = (float*)d_out;

    const int N = NNODES;
    const int E = in_sizes[1] / 2;      // 1,600,000
    const int TOTAL = E + N;
    const int* srcv = ei;
    const int* dstv = ei + E;

    char* p = (char*)d_ws;
    auto carve = [&](size_t bytes) {
        void* r = (void*)p;
        p += (bytes + 255) & ~(size_t)255;
        return r;
    };
    int*   cnt       = (int*)carve((size_t)N * 4);
    int*   row_start = (int*)carve((size_t)(N + 1) * 4);
    int*   cursor    = (int*)carve((size_t)N * 4);
    int*   bsum      = (int*)carve(512);
    int*   boff      = (int*)carve(512 + 4);
    int*   csr_src   = (int*)carve((size_t)TOTAL * 4);
    float* dinv      = (float*)carve((size_t)N * 4);
    unsigned short* W1T  = (unsigned short*)carve((size_t)F_MID * KPAD * 2);
    unsigned short* W2T  = (unsigned short*)carve((size_t)H2S * F_MID * 2);
    unsigned short* h1b  = (unsigned short*)carve((size_t)N * F_MID * 2);
    unsigned short* out1b= (unsigned short*)carve((size_t)N * F_MID * 2);
    unsigned short* h2b  = (unsigned short*)carve((size_t)N * H2S * 2);
    (void)ws_size; (void)n_in; (void)out_size;

    const int nb = (N + 1023) / 1024;   // 98

    hipMemsetAsync(cnt, 0, (size_t)N * 4, stream);
    hist_kernel<<<(E + 255) / 256, 256, 0, stream>>>(dstv, cnt, E);
    scan_local<<<nb, 1024, 0, stream>>>(cnt, row_start, bsum, N);
    scan_bsum<<<1, 128, 0, stream>>>(bsum, boff, nb);
    scan_apply<<<nb, 1024, 0, stream>>>(cnt, row_start, cursor, dinv, boff, N, nb);
    fill_kernel<<<(TOTAL + 255) / 256, 256, 0, stream>>>(srcv, dstv, cursor, csr_src, E, TOTAL);
    w1t_prep<<<(F_MID * KPAD + 255) / 256, 256, 0, stream>>>(W1, W1T);
    w2t_prep<<<(H2S * F_MID + 255) / 256, 256, 0, stream>>>(W2, W2T);

    gemm1_kernel<<<(N + 127) / 128, 256, 0, stream>>>(X, W1T, dinv, h1b);
    agg1_kernel<<<N / 4, 256, 0, stream>>>(h1b, csr_src, row_start, dinv, b1, out1b);
    gemm2_kernel<<<(N + 63) / 64, 256, 0, stream>>>(out1b, W2T, dinv, h2b);
    agg2_softmax_kernel<<<N / 4, 256, 0, stream>>>(h2b, csr_src, row_start, dinv, b2, out);
}